// Round 11
// baseline (226.051 us; speedup 1.0000x reference)
//
#include <hip/hip_runtime.h>

// ---------------- problem constants ----------------
#define B_  2
#define N_  8192
#define I_  32
#define E_  128
#define H_  64
#define BN_ (B_*N_)          // 16384
#define NW_ (N_/64)          // 128 u64 words per (b,i) mask row

typedef unsigned long long u64;

// ---------------- module-scope device state (fully rewritten every launch) -----
__device__ float g_pe  [B_*I_*E_];     // pos_embed
__device__ float g_v1  [B_*I_*H_];     // decode hidden bias, initial
__device__ float g_v2  [B_*I_*H_];     // decode hidden bias, refined
__device__ float g_wd1t[E_*H_];        // Wd1 transposed [e][k]
__device__ float g_upart[8*H_*BN_];    // u partials [pt][k][p] (32 MB)
__device__ float g_u   [H_*BN_];       // u[k][p] (4 MB, k-major -> coalesced)
__device__ u64   g_masks[B_*I_*NW_];   // initial masks as bitwords (64 KB)
__device__ int   g_inter[B_*I_*I_];    // intersection counts (diag = m_sum)

// ---------------- jax threefry2x32, key = key(42) = (0,42) ----------------
__device__ __forceinline__ unsigned rotl_(unsigned x, unsigned n){ return (x<<n)|(x>>(32u-n)); }

__device__ void threefry_42(unsigned x0, unsigned x1, unsigned* r0, unsigned* r1){
  const unsigned ks0 = 0u, ks1 = 42u, ks2 = 0x1BD11BDAu ^ 0u ^ 42u;
  x0 += ks0; x1 += ks1;
  x0+=x1; x1=rotl_(x1,13); x1^=x0;
  x0+=x1; x1=rotl_(x1,15); x1^=x0;
  x0+=x1; x1=rotl_(x1,26); x1^=x0;
  x0+=x1; x1=rotl_(x1, 6); x1^=x0;
  x0+=ks1; x1+=ks2+1u;
  x0+=x1; x1=rotl_(x1,17); x1^=x0;
  x0+=x1; x1=rotl_(x1,29); x1^=x0;
  x0+=x1; x1=rotl_(x1,16); x1^=x0;
  x0+=x1; x1=rotl_(x1,24); x1^=x0;
  x0+=ks2; x1+=ks0+2u;
  x0+=x1; x1=rotl_(x1,13); x1^=x0;
  x0+=x1; x1=rotl_(x1,15); x1^=x0;
  x0+=x1; x1=rotl_(x1,26); x1^=x0;
  x0+=x1; x1=rotl_(x1, 6); x1^=x0;
  x0+=ks0; x1+=ks1+3u;
  x0+=x1; x1=rotl_(x1,17); x1^=x0;
  x0+=x1; x1=rotl_(x1,29); x1^=x0;
  x0+=x1; x1=rotl_(x1,16); x1^=x0;
  x0+=x1; x1=rotl_(x1,24); x1^=x0;
  x0+=ks1; x1+=ks2+4u;
  x0+=x1; x1=rotl_(x1,13); x1^=x0;
  x0+=x1; x1=rotl_(x1,15); x1^=x0;
  x0+=x1; x1=rotl_(x1,26); x1^=x0;
  x0+=x1; x1=rotl_(x1, 6); x1^=x0;
  x0+=ks2; x1+=ks0+5u;
  *r0 = x0; *r1 = x1;
}

// element e of jax.random.uniform(key(42), (2,32,32), 1e-20, 1.0)
// PARTITIONABLE threefry (VERIFIED r7): counter (0,e), bits = out0 ^ out1.
__device__ float jax_uniform_2048(int e){
  unsigned o0, o1;
  threefry_42(0u, (unsigned)e, &o0, &o1);
  unsigned bits = o0 ^ o1;
  float u = __uint_as_float((bits >> 9) | 0x3f800000u) - 1.0f;
  u = u + 1e-20f;
  return fmaxf(1e-20f, u);
}

// ---------------- K0: pos_embed + Wd1^T + v1 (1 block) ----------------
__global__ void __launch_bounds__(256) prep_kernel(
    const float* __restrict__ pos_coords,
    const float* __restrict__ Wp, const float* __restrict__ bp,
    const float* __restrict__ Wd1,const float* __restrict__ bd1)
{
  __shared__ float t_l[E_*65];       // Wd1^T tile [e][k], pad 65
  const int tid = threadIdx.x;

  for (int idx = tid; idx < H_*E_; idx += 256){
    int k = idx >> 7, e = idx & 127;           // lanes: e consecutive
    t_l[e*65 + k] = Wd1[idx];
  }
  for (int idx = tid; idx < B_*I_*E_; idx += 256){
    int row = idx >> 7, e = idx & 127;
    float s = pos_coords[row*3+0] * Wp[e*3+0];
    s = fmaf(pos_coords[row*3+1], Wp[e*3+1], s);
    s = fmaf(pos_coords[row*3+2], Wp[e*3+2], s);
    g_pe[idx] = s + bp[e];
  }
  __syncthreads();

  for (int idx = tid; idx < E_*H_; idx += 256){
    int e = idx >> 6, k = idx & 63;
    g_wd1t[idx] = t_l[e*65 + k];
  }
  for (int idx = tid; idx < B_*I_*H_; idx += 256){
    int row = idx >> 6, k = idx & 63;
    float s = 0.f;
    for (int e = 0; e < 128; ++e)
      s = fmaf(g_pe[row*128 + e], t_l[e*65 + k], s);
    g_v1[idx] = s + bd1[k];
  }
}

// ---------------- K1: encoder, e-split across 512 blocks ----------------
// block = (h = eIdx half, 64 points); wave w covers e in [h*64+w*16, +16)
__global__ void __launch_bounds__(256) enc_kernel(
    const float* __restrict__ points,
    const float* __restrict__ W1, const float* __restrict__ A1,
    const float* __restrict__ B1, const float* __restrict__ W2,
    const float* __restrict__ A2, const float* __restrict__ B2,
    float* __restrict__ out_pf)
{
  __shared__ float pf_l[64*65];      // [e'][point] for this block's 64 e: 16.6 KB
  const int tid  = threadIdx.x;
  const int w_u  = __builtin_amdgcn_readfirstlane(tid >> 6);
  const int lane = tid & 63;
  const int pc   = blockIdx.x & 255;           // point-chunk
  const int h    = blockIdx.x >> 8;            // e-half 0/1
  const int p0   = pc * 64;
  const int p    = p0 + lane;

  const float x0 = points[p*3+0];
  const float x1 = points[p*3+1];
  const float x2 = points[p*3+2];

  float a1[4];
  #pragma unroll
  for (int r = 0; r < 4; ++r){
    float s = x0 * A1[r*3+0];
    s = fmaf(x1, A1[r*3+1], s);
    s = fmaf(x2, A1[r*3+2], s);
    a1[r] = s;
  }
  float t1[64];
  #pragma unroll
  for (int k = 0; k < 64; ++k){
    float s = x0 * W1[k*3+0];
    s = fmaf(x1, W1[k*3+1], s);
    s = fmaf(x2, W1[k*3+2], s);
    float l = a1[0] * B1[k*4+0];
    l = fmaf(a1[1], B1[k*4+1], l);
    l = fmaf(a1[2], B1[k*4+2], l);
    l = fmaf(a1[3], B1[k*4+3], l);
    t1[k] = fmaxf(fmaf(0.25f, l, s), 0.0f);
  }
  float a2[4];
  #pragma unroll
  for (int r = 0; r < 4; ++r){
    float s = 0.f;
    #pragma unroll
    for (int j = 0; j < 64; ++j) s = fmaf(t1[j], A2[r*64+j], s);
    a2[r] = s;
  }
  float u_p[64];
  #pragma unroll
  for (int k = 0; k < 64; ++k) u_p[k] = 0.f;

  const int e0 = h*64 + w_u*16;
  for (int ei = 0; ei < 16; ++ei){
    const int e = e0 + ei;                     // wave-uniform -> scalar loads
    float s1 = 0.f;
    #pragma unroll
    for (int j = 0; j < 64; ++j) s1 = fmaf(t1[j], W2[e*64+j], s1);
    float s2 = a2[0] * B2[e*4+0];
    s2 = fmaf(a2[1], B2[e*4+1], s2);
    s2 = fmaf(a2[2], B2[e*4+2], s2);
    s2 = fmaf(a2[3], B2[e*4+3], s2);
    const float pf = fmaf(0.25f, s2, s1);
    pf_l[(w_u*16 + ei)*65 + lane] = pf;        // conflict-free
    #pragma unroll
    for (int k = 0; k < 64; ++k) u_p[k] = fmaf(pf, g_wd1t[e*64+k], u_p[k]);
  }

  // partial-u store: partial index pt = h*4+w covers e-chunk in e-order
  float* up = g_upart + (size_t)(h*4 + w_u) * H_ * BN_;
  #pragma unroll
  for (int k = 0; k < 64; ++k)
    up[(size_t)k * BN_ + p] = u_p[k];          // lane-coalesced

  __syncthreads();
  // coalesced pf store of this block's 64-e half
  for (int idx = tid; idx < 64*64; idx += 256){
    const int pt = idx >> 6, ep = idx & 63;
    out_pf[(size_t)(p0 + pt) * E_ + h*64 + ep] = pf_l[ep*65 + pt];
  }
}

// ---------------- K1b: reduce u partials + initial ballot (256 blocks) --------
__global__ void __launch_bounds__(256) fin_kernel(
    const float* __restrict__ Wd2, const float* __restrict__ bd2)
{
  __shared__ float u_l[64*65];       // [point][k]
  const int tid  = threadIdx.x;
  const int w_u  = __builtin_amdgcn_readfirstlane(tid >> 6);
  const int lane = tid & 63;
  const int p0   = blockIdx.x * 64;
  const int b    = blockIdx.x >> 7;

  // reduce 8 partials in pt-order (= e-order: bit-identical to staged reduction)
  for (int idx = tid; idx < 64*64; idx += 256){
    const int k = idx >> 6, pl = idx & 63;     // lanes: pl consecutive -> coalesced
    const size_t off = (size_t)k * BN_ + p0 + pl;
    float s = g_upart[off];
    #pragma unroll
    for (int pt = 1; pt < 8; ++pt)
      s += g_upart[(size_t)pt * H_ * BN_ + off];
    g_u[off] = s;
    u_l[pl*65 + k] = s;
  }
  __syncthreads();

  // initial decode + ballot; acc[ii] sums k sequentially (bit-identical)
  const float bd2v = bd2[0];
  float acc[8];
  #pragma unroll
  for (int ii = 0; ii < 8; ++ii) acc[ii] = 0.f;
  const float* v = g_v1 + ((b * I_ + w_u * 8) << 6);
  for (int k = 0; k < 64; ++k){
    const float wd2k = Wd2[k];
    const float uk = u_l[lane*65 + k];
    #pragma unroll
    for (int ii = 0; ii < 8; ++ii)
      acc[ii] = fmaf(wd2k, fmaxf(uk + v[ii*64 + k], 0.0f), acc[ii]);
  }
  #pragma unroll
  for (int ii = 0; ii < 8; ++ii){
    const int i = w_u * 8 + ii;
    u64 bal = __ballot(acc[ii] + bd2v > 0.0f);
    if (lane == 0) g_masks[(size_t)(b * I_ + i) * NW_ + (blockIdx.x & 127)] = bal;
  }
}

// ---------------- K2a: inter[r][j] = popcount(m_r & m_j), 64 blocks ----------------
__global__ void __launch_bounds__(256) inter_kernel()
{
  const int r   = blockIdx.x;          // 0..63
  const int b   = r >> 5;
  const int tid = threadIdx.x;
  const int j   = tid >> 3;            // 0..31
  const int ws  = (tid & 7) * 16;      // word segment base
  const u64* mi = g_masks + (size_t)r * NW_;
  const u64* mj = g_masks + (size_t)(b*32 + j) * NW_;
  int s = 0;
  #pragma unroll
  for (int w = 0; w < 16; ++w)
    s += __popcll(mi[ws + w] & mj[ws + w]);
  s += __shfl_xor(s, 1, 64);
  s += __shfl_xor(s, 2, 64);
  s += __shfl_xor(s, 4, 64);
  if ((tid & 7) == 0) g_inter[r*32 + j] = s;
}

// ---------------- K2b: Gumbel-max sampling + v2 (1 block) ----------------
__global__ void __launch_bounds__(256) sample_kernel(
    const float* __restrict__ pos_coords,
    const float* __restrict__ Wp, const float* __restrict__ bp,
    const float* __restrict__ bd1)
{
  __shared__ int   inter_l[2048];
  __shared__ float delta_l[64*129];
  __shared__ float nc_l[64][3];
  const int tid = threadIdx.x;

  for (int idx = tid; idx < 2048; idx += 256) inter_l[idx] = g_inter[idx];
  __syncthreads();

  if (tid < 64){
    const int b = tid >> 5;
    const int i = tid & 31;
    const int msum_i = inter_l[(b << 10) + (i << 5) + i];   // diag = m_sum
    float best = -INFINITY; int bestj = 0; bool any = false;
    for (int j = 0; j < 32; ++j){
      const int inter = inter_l[(b << 10) + (i << 5) + j];
      const int msum_j = inter_l[(b << 10) + (j << 5) + j];
      const int uni   = msum_i + msum_j - inter;
      // EXACT f32 mimicry of the reference: inter/(union+1e-6) in f32.
      const float iou = (float)inter / ((float)uni + 1e-6f);
      const bool cand = (j != i) && (iou >= 0.1f);
      if (cand){
        any = true;
        const float uu = jax_uniform_2048((tid << 5) + j);
        const float g  = -logf(-logf(uu));
        if (g > best){ best = g; bestj = j; }            // first-max like argmax
      }
    }
    nc_l[tid][0] = any ? pos_coords[(b*32 + bestj)*3 + 0] : 0.f;
    nc_l[tid][1] = any ? pos_coords[(b*32 + bestj)*3 + 1] : 0.f;
    nc_l[tid][2] = any ? pos_coords[(b*32 + bestj)*3 + 2] : 0.f;
  }
  __syncthreads();

  for (int idx = tid; idx < 64*E_; idx += 256){
    const int row = idx >> 7, e = idx & 127;
    float ne = nc_l[row][0] * Wp[e*3+0];
    ne = fmaf(nc_l[row][1], Wp[e*3+1], ne);
    ne = fmaf(nc_l[row][2], Wp[e*3+2], ne);
    ne = ne + bp[e];                                     // == bp when invalid
    delta_l[row*129 + e] = g_pe[row*128 + e] - ne;
  }
  __syncthreads();

  for (int idx = tid; idx < B_*I_*H_; idx += 256){
    const int row = idx >> 6, k = idx & 63;
    float s = 0.f;
    for (int e = 0; e < 128; ++e)
      s = fmaf(delta_l[row*129 + e], g_wd1t[e*64 + k], s);
    g_v2[idx] = s + bd1[k];
  }
}

// ---------------- K3: refined decode (k-outer, 8 independent acc chains) ------
__global__ void __launch_bounds__(256) dec_kernel(
    const float* __restrict__ Wd2, const float* __restrict__ bd2,
    float* __restrict__ out0)
{
  const int tid  = threadIdx.x;
  const int w_u  = __builtin_amdgcn_readfirstlane(tid >> 6);
  const int lane = tid & 63;
  const int bc   = blockIdx.x;           // 256 blocks
  const int b    = bc >> 7;
  const int nb   = (bc & 127) << 6;
  const int n    = nb + lane;
  const int p    = b * N_ + n;

  float u[64];
  #pragma unroll
  for (int k = 0; k < 64; ++k) u[k] = g_u[(size_t)k * BN_ + p];   // coalesced

  const float bd2v = bd2[0];
  float acc[8];
  #pragma unroll
  for (int ii = 0; ii < 8; ++ii) acc[ii] = 0.f;
  const float* v = g_v2 + ((b * I_ + w_u * 8) << 6);
  for (int k = 0; k < 64; ++k){
    const float wd2k = Wd2[k];
    const float uk = u[k];
    #pragma unroll
    for (int ii = 0; ii < 8; ++ii)
      acc[ii] = fmaf(wd2k, fmaxf(uk + v[ii*64 + k], 0.0f), acc[ii]);
  }
  #pragma unroll
  for (int ii = 0; ii < 8; ++ii){
    const int i = w_u * 8 + ii;
    out0[(size_t)(b * I_ + i) * N_ + n] = acc[ii] + bd2v;
  }
}

// ---------------- launch ----------------
extern "C" void kernel_launch(void* const* d_in, const int* in_sizes, int n_in,
                              void* d_out, int out_size, void* d_ws, size_t ws_size,
                              hipStream_t stream)
{
  (void)in_sizes; (void)n_in; (void)out_size; (void)d_ws; (void)ws_size;
  const float* points     = (const float*)d_in[0];
  const float* pos_coords = (const float*)d_in[1];
  const float* W1  = (const float*)d_in[2];
  const float* A1  = (const float*)d_in[3];
  const float* B1  = (const float*)d_in[4];
  const float* W2  = (const float*)d_in[5];
  const float* A2  = (const float*)d_in[6];
  const float* B2  = (const float*)d_in[7];
  const float* Wp  = (const float*)d_in[8];
  const float* bp  = (const float*)d_in[9];
  const float* Wd1 = (const float*)d_in[10];
  const float* bd1 = (const float*)d_in[11];
  const float* Wd2 = (const float*)d_in[12];
  const float* bd2 = (const float*)d_in[13];

  float* out0   = (float*)d_out;                        // refined_logits [B,I,N]
  float* out_pf = out0 + (size_t)B_ * I_ * N_;          // point_feats   [B,N,E]

  prep_kernel<<<1, 256, 0, stream>>>(pos_coords, Wp, bp, Wd1, bd1);
  enc_kernel<<<512, 256, 0, stream>>>(points, W1, A1, B1, W2, A2, B2, out_pf);
  fin_kernel<<<256, 256, 0, stream>>>(Wd2, bd2);
  inter_kernel<<<64, 256, 0, stream>>>();
  sample_kernel<<<1, 256, 0, stream>>>(pos_coords, Wp, bp, bd1);
  dec_kernel<<<256, 256, 0, stream>>>(Wd2, bd2, out0);
}

// Round 12
// 185.563 us; speedup vs baseline: 1.2182x; 1.2182x over previous
//
#include <hip/hip_runtime.h>

// ---------------- problem constants ----------------
#define B_  2
#define N_  8192
#define I_  32
#define E_  128
#define H_  64
#define BN_ (B_*N_)          // 16384
#define NW_ (N_/64)          // 128 u64 words per (b,i) mask row

typedef unsigned long long u64;

// ---------------- module-scope device state (fully rewritten every launch) -----
__device__ float g_pe  [B_*I_*E_];     // pos_embed
__device__ float g_v1  [B_*I_*H_];     // decode hidden bias, initial
__device__ float g_v2  [B_*I_*H_];     // decode hidden bias, refined
__device__ float g_wd1t[E_*H_];        // Wd1 transposed [e][k]
__device__ float g_upart[2*H_*BN_];    // u half-sums [h][k][p] (8 MB)
__device__ float g_u   [H_*BN_];       // u[k][p] (4 MB, k-major -> coalesced)
__device__ u64   g_masks[B_*I_*NW_];   // initial masks as bitwords (64 KB)
__device__ int   g_inter[B_*I_*I_];    // intersection counts (diag = m_sum)

// ---------------- jax threefry2x32, key = key(42) = (0,42) ----------------
__device__ __forceinline__ unsigned rotl_(unsigned x, unsigned n){ return (x<<n)|(x>>(32u-n)); }

__device__ void threefry_42(unsigned x0, unsigned x1, unsigned* r0, unsigned* r1){
  const unsigned ks0 = 0u, ks1 = 42u, ks2 = 0x1BD11BDAu ^ 0u ^ 42u;
  x0 += ks0; x1 += ks1;
  x0+=x1; x1=rotl_(x1,13); x1^=x0;
  x0+=x1; x1=rotl_(x1,15); x1^=x0;
  x0+=x1; x1=rotl_(x1,26); x1^=x0;
  x0+=x1; x1=rotl_(x1, 6); x1^=x0;
  x0+=ks1; x1+=ks2+1u;
  x0+=x1; x1=rotl_(x1,17); x1^=x0;
  x0+=x1; x1=rotl_(x1,29); x1^=x0;
  x0+=x1; x1=rotl_(x1,16); x1^=x0;
  x0+=x1; x1=rotl_(x1,24); x1^=x0;
  x0+=ks2; x1+=ks0+2u;
  x0+=x1; x1=rotl_(x1,13); x1^=x0;
  x0+=x1; x1=rotl_(x1,15); x1^=x0;
  x0+=x1; x1=rotl_(x1,26); x1^=x0;
  x0+=x1; x1=rotl_(x1, 6); x1^=x0;
  x0+=ks0; x1+=ks1+3u;
  x0+=x1; x1=rotl_(x1,17); x1^=x0;
  x0+=x1; x1=rotl_(x1,29); x1^=x0;
  x0+=x1; x1=rotl_(x1,16); x1^=x0;
  x0+=x1; x1=rotl_(x1,24); x1^=x0;
  x0+=ks1; x1+=ks2+4u;
  x0+=x1; x1=rotl_(x1,13); x1^=x0;
  x0+=x1; x1=rotl_(x1,15); x1^=x0;
  x0+=x1; x1=rotl_(x1,26); x1^=x0;
  x0+=x1; x1=rotl_(x1, 6); x1^=x0;
  x0+=ks2; x1+=ks0+5u;
  *r0 = x0; *r1 = x1;
}

// element e of jax.random.uniform(key(42), (2,32,32), 1e-20, 1.0)
// PARTITIONABLE threefry (VERIFIED r7): counter (0,e), bits = out0 ^ out1.
__device__ float jax_uniform_2048(int e){
  unsigned o0, o1;
  threefry_42(0u, (unsigned)e, &o0, &o1);
  unsigned bits = o0 ^ o1;
  float u = __uint_as_float((bits >> 9) | 0x3f800000u) - 1.0f;
  u = u + 1e-20f;
  return fmaxf(1e-20f, u);
}

// ---------------- K0: pos_embed + Wd1^T + v1 (1 block) ----------------
__global__ void __launch_bounds__(256) prep_kernel(
    const float* __restrict__ pos_coords,
    const float* __restrict__ Wp, const float* __restrict__ bp,
    const float* __restrict__ Wd1,const float* __restrict__ bd1)
{
  __shared__ float t_l [E_*65];      // Wd1^T tile [e][k], pad 65: 33.3 KB
  __shared__ float pe_l[B_*I_*E_];   // pos_embed mirror: 32 KB
  const int tid = threadIdx.x;

  for (int idx = tid; idx < H_*E_; idx += 256){
    int k = idx >> 7, e = idx & 127;           // lanes: e consecutive
    t_l[e*65 + k] = Wd1[idx];
  }
  for (int idx = tid; idx < B_*I_*E_; idx += 256){
    int row = idx >> 7, e = idx & 127;
    float s = pos_coords[row*3+0] * Wp[e*3+0];
    s = fmaf(pos_coords[row*3+1], Wp[e*3+1], s);
    s = fmaf(pos_coords[row*3+2], Wp[e*3+2], s);
    const float pe = s + bp[e];
    g_pe[idx]  = pe;
    pe_l[idx]  = pe;
  }
  __syncthreads();

  for (int idx = tid; idx < E_*H_; idx += 256){
    int e = idx >> 6, k = idx & 63;
    g_wd1t[idx] = t_l[e*65 + k];
  }
  // v1: pure LDS inner loop (pe_l broadcast, t_l conflict-free)
  for (int idx = tid; idx < B_*I_*H_; idx += 256){
    int row = idx >> 6, k = idx & 63;
    float s = 0.f;
    for (int e = 0; e < 128; ++e)
      s = fmaf(pe_l[row*128 + e], t_l[e*65 + k], s);
    g_v1[idx] = s + bd1[k];
  }
}

// ---------------- K1: encoder, e-split across 512 blocks ----------------
// block = (h = e-half, 64 points); wave w covers e in [h*64+w*16, +16)
// in-block reduction of the 4 wave partials -> one half-sum per block
__global__ void __launch_bounds__(256) enc_kernel(
    const float* __restrict__ points,
    const float* __restrict__ W1, const float* __restrict__ A1,
    const float* __restrict__ B1, const float* __restrict__ W2,
    const float* __restrict__ A2, const float* __restrict__ B2,
    float* __restrict__ out_pf)
{
  __shared__ float pf_l[64*65];      // [e'][point]: 16.6 KB
  __shared__ float u_l [64*65];      // [point][k]:  16.6 KB
  const int tid  = threadIdx.x;
  const int w_u  = __builtin_amdgcn_readfirstlane(tid >> 6);
  const int lane = tid & 63;
  const int pc   = blockIdx.x & 255;           // point-chunk
  const int h    = blockIdx.x >> 8;            // e-half 0/1
  const int p0   = pc * 64;
  const int p    = p0 + lane;

  const float x0 = points[p*3+0];
  const float x1 = points[p*3+1];
  const float x2 = points[p*3+2];

  float a1[4];
  #pragma unroll
  for (int r = 0; r < 4; ++r){
    float s = x0 * A1[r*3+0];
    s = fmaf(x1, A1[r*3+1], s);
    s = fmaf(x2, A1[r*3+2], s);
    a1[r] = s;
  }
  float t1[64];
  #pragma unroll
  for (int k = 0; k < 64; ++k){
    float s = x0 * W1[k*3+0];
    s = fmaf(x1, W1[k*3+1], s);
    s = fmaf(x2, W1[k*3+2], s);
    float l = a1[0] * B1[k*4+0];
    l = fmaf(a1[1], B1[k*4+1], l);
    l = fmaf(a1[2], B1[k*4+2], l);
    l = fmaf(a1[3], B1[k*4+3], l);
    t1[k] = fmaxf(fmaf(0.25f, l, s), 0.0f);
  }
  float a2[4];
  #pragma unroll
  for (int r = 0; r < 4; ++r){
    float s = 0.f;
    #pragma unroll
    for (int j = 0; j < 64; ++j) s = fmaf(t1[j], A2[r*64+j], s);
    a2[r] = s;
  }
  float u_p[64];
  #pragma unroll
  for (int k = 0; k < 64; ++k) u_p[k] = 0.f;

  const int e0 = h*64 + w_u*16;
  for (int ei = 0; ei < 16; ++ei){
    const int e = e0 + ei;                     // wave-uniform -> scalar loads
    float s1 = 0.f;
    #pragma unroll
    for (int j = 0; j < 64; ++j) s1 = fmaf(t1[j], W2[e*64+j], s1);
    float s2 = a2[0] * B2[e*4+0];
    s2 = fmaf(a2[1], B2[e*4+1], s2);
    s2 = fmaf(a2[2], B2[e*4+2], s2);
    s2 = fmaf(a2[3], B2[e*4+3], s2);
    const float pf = fmaf(0.25f, s2, s1);
    pf_l[(w_u*16 + ei)*65 + lane] = pf;        // conflict-free
    #pragma unroll
    for (int k = 0; k < 64; ++k) u_p[k] = fmaf(pf, g_wd1t[e*64+k], u_p[k]);
  }

  // staged in-block reduction, pass-order = within-half e-order
  for (int pass = 0; pass < 4; ++pass){
    if (w_u == pass){
      if (pass == 0){
        #pragma unroll
        for (int k = 0; k < 64; ++k) u_l[lane*65 + k] = u_p[k];
      } else {
        #pragma unroll
        for (int k = 0; k < 64; ++k) u_l[lane*65 + k] += u_p[k];
      }
    }
    __syncthreads();
  }

  // coalesced half-sum store [h][k][p]
  for (int idx = tid; idx < 64*64; idx += 256){
    const int k = idx >> 6, pl = idx & 63;
    g_upart[(size_t)h * H_ * BN_ + (size_t)k * BN_ + p0 + pl] = u_l[pl*65 + k];
  }
  // coalesced pf store of this block's 64-e half
  for (int idx = tid; idx < 64*64; idx += 256){
    const int pt = idx >> 6, ep = idx & 63;
    out_pf[(size_t)(p0 + pt) * E_ + h*64 + ep] = pf_l[ep*65 + pt];
  }
}

// ---------------- K1b: u = h0+h1, initial ballot (256 blocks) --------
__global__ void __launch_bounds__(256) fin_kernel(
    const float* __restrict__ Wd2, const float* __restrict__ bd2)
{
  __shared__ float u_l[64*65];       // [point][k]
  const int tid  = threadIdx.x;
  const int w_u  = __builtin_amdgcn_readfirstlane(tid >> 6);
  const int lane = tid & 63;
  const int p0   = blockIdx.x * 64;
  const int b    = blockIdx.x >> 7;

  for (int idx = tid; idx < 64*64; idx += 256){
    const int k = idx >> 6, pl = idx & 63;     // lanes: pl consecutive -> coalesced
    const size_t off = (size_t)k * BN_ + p0 + pl;
    float s = g_upart[off];                    // h0
    s += g_upart[(size_t)H_ * BN_ + off];      // + h1 (e-order halves)
    g_u[off] = s;
    u_l[pl*65 + k] = s;
  }
  __syncthreads();

  const float bd2v = bd2[0];
  float acc[8];
  #pragma unroll
  for (int ii = 0; ii < 8; ++ii) acc[ii] = 0.f;
  const float* v = g_v1 + ((b * I_ + w_u * 8) << 6);
  for (int k = 0; k < 64; ++k){
    const float wd2k = Wd2[k];
    const float uk = u_l[lane*65 + k];
    #pragma unroll
    for (int ii = 0; ii < 8; ++ii)
      acc[ii] = fmaf(wd2k, fmaxf(uk + v[ii*64 + k], 0.0f), acc[ii]);
  }
  #pragma unroll
  for (int ii = 0; ii < 8; ++ii){
    const int i = w_u * 8 + ii;
    u64 bal = __ballot(acc[ii] + bd2v > 0.0f);
    if (lane == 0) g_masks[(size_t)(b * I_ + i) * NW_ + (blockIdx.x & 127)] = bal;
  }
}

// ---------------- K2a: inter[r][j] = popcount(m_r & m_j), 64 blocks ----------------
__global__ void __launch_bounds__(256) inter_kernel()
{
  const int r   = blockIdx.x;          // 0..63
  const int b   = r >> 5;
  const int tid = threadIdx.x;
  const int j   = tid >> 3;            // 0..31
  const int ws  = (tid & 7) * 16;      // word segment base
  const u64* mi = g_masks + (size_t)r * NW_;
  const u64* mj = g_masks + (size_t)(b*32 + j) * NW_;
  int s = 0;
  #pragma unroll
  for (int w = 0; w < 16; ++w)
    s += __popcll(mi[ws + w] & mj[ws + w]);
  s += __shfl_xor(s, 1, 64);
  s += __shfl_xor(s, 2, 64);
  s += __shfl_xor(s, 4, 64);
  if ((tid & 7) == 0) g_inter[r*32 + j] = s;
}

// ---------------- K2b: Gumbel-max sampling + v2 (1 block) ----------------
__global__ void __launch_bounds__(256) sample_kernel(
    const float* __restrict__ pos_coords,
    const float* __restrict__ Wp, const float* __restrict__ bp,
    const float* __restrict__ bd1)
{
  __shared__ int   inter_l[2048];
  __shared__ float delta_l[64*129];
  __shared__ float nc_l[64][3];
  __shared__ float wd1t_l[E_*H_];    // 32 KB: wd1t mirror
  const int tid = threadIdx.x;

  for (int idx = tid; idx < 2048; idx += 256) inter_l[idx] = g_inter[idx];
  for (int idx = tid; idx < E_*H_; idx += 256) wd1t_l[idx] = g_wd1t[idx];
  __syncthreads();

  if (tid < 64){
    const int b = tid >> 5;
    const int i = tid & 31;
    const int msum_i = inter_l[(b << 10) + (i << 5) + i];   // diag = m_sum
    float best = -INFINITY; int bestj = 0; bool any = false;
    for (int j = 0; j < 32; ++j){
      const int inter = inter_l[(b << 10) + (i << 5) + j];
      const int msum_j = inter_l[(b << 10) + (j << 5) + j];
      const int uni   = msum_i + msum_j - inter;
      // EXACT f32 mimicry of the reference: inter/(union+1e-6) in f32.
      const float iou = (float)inter / ((float)uni + 1e-6f);
      const bool cand = (j != i) && (iou >= 0.1f);
      if (cand){
        any = true;
        const float uu = jax_uniform_2048((tid << 5) + j);
        const float g  = -logf(-logf(uu));
        if (g > best){ best = g; bestj = j; }            // first-max like argmax
      }
    }
    nc_l[tid][0] = any ? pos_coords[(b*32 + bestj)*3 + 0] : 0.f;
    nc_l[tid][1] = any ? pos_coords[(b*32 + bestj)*3 + 1] : 0.f;
    nc_l[tid][2] = any ? pos_coords[(b*32 + bestj)*3 + 2] : 0.f;
  }
  __syncthreads();

  for (int idx = tid; idx < 64*E_; idx += 256){
    const int row = idx >> 7, e = idx & 127;
    float ne = nc_l[row][0] * Wp[e*3+0];
    ne = fmaf(nc_l[row][1], Wp[e*3+1], ne);
    ne = fmaf(nc_l[row][2], Wp[e*3+2], ne);
    ne = ne + bp[e];                                     // == bp when invalid
    delta_l[row*129 + e] = g_pe[row*128 + e] - ne;
  }
  __syncthreads();

  // v2: pure LDS inner loop
  for (int idx = tid; idx < B_*I_*H_; idx += 256){
    const int row = idx >> 6, k = idx & 63;
    float s = 0.f;
    for (int e = 0; e < 128; ++e)
      s = fmaf(delta_l[row*129 + e], wd1t_l[e*64 + k], s);
    g_v2[idx] = s + bd1[k];
  }
}

// ---------------- K3: refined decode (512 blocks, i-halves) ------
__global__ void __launch_bounds__(256) dec_kernel(
    const float* __restrict__ Wd2, const float* __restrict__ bd2,
    float* __restrict__ out0)
{
  const int tid  = threadIdx.x;
  const int w_u  = __builtin_amdgcn_readfirstlane(tid >> 6);
  const int lane = tid & 63;
  const int bc   = blockIdx.x;           // 512 blocks
  const int b    = bc >> 8;
  const int nb   = (bc & 127) << 6;
  const int ih   = (bc >> 7) & 1;        // i-half
  const int n    = nb + lane;
  const int p    = b * N_ + n;

  float u[64];
  #pragma unroll
  for (int k = 0; k < 64; ++k) u[k] = g_u[(size_t)k * BN_ + p];   // coalesced

  const float bd2v = bd2[0];
  float acc[4];
  #pragma unroll
  for (int ii = 0; ii < 4; ++ii) acc[ii] = 0.f;
  const int ibase = ih * 16 + w_u * 4;
  const float* v = g_v2 + ((b * I_ + ibase) << 6);
  for (int k = 0; k < 64; ++k){
    const float wd2k = Wd2[k];
    const float uk = u[k];
    #pragma unroll
    for (int ii = 0; ii < 4; ++ii)
      acc[ii] = fmaf(wd2k, fmaxf(uk + v[ii*64 + k], 0.0f), acc[ii]);
  }
  #pragma unroll
  for (int ii = 0; ii < 4; ++ii){
    const int i = ibase + ii;
    out0[(size_t)(b * I_ + i) * N_ + n] = acc[ii] + bd2v;
  }
}

// ---------------- launch ----------------
extern "C" void kernel_launch(void* const* d_in, const int* in_sizes, int n_in,
                              void* d_out, int out_size, void* d_ws, size_t ws_size,
                              hipStream_t stream)
{
  (void)in_sizes; (void)n_in; (void)out_size; (void)d_ws; (void)ws_size;
  const float* points     = (const float*)d_in[0];
  const float* pos_coords = (const float*)d_in[1];
  const float* W1  = (const float*)d_in[2];
  const float* A1  = (const float*)d_in[3];
  const float* B1  = (const float*)d_in[4];
  const float* W2  = (const float*)d_in[5];
  const float* A2  = (const float*)d_in[6];
  const float* B2  = (const float*)d_in[7];
  const float* Wp  = (const float*)d_in[8];
  const float* bp  = (const float*)d_in[9];
  const float* Wd1 = (const float*)d_in[10];
  const float* bd1 = (const float*)d_in[11];
  const float* Wd2 = (const float*)d_in[12];
  const float* bd2 = (const float*)d_in[13];

  float* out0   = (float*)d_out;                        // refined_logits [B,I,N]
  float* out_pf = out0 + (size_t)B_ * I_ * N_;          // point_feats   [B,N,E]

  prep_kernel<<<1, 256, 0, stream>>>(pos_coords, Wp, bp, Wd1, bd1);
  enc_kernel<<<512, 256, 0, stream>>>(points, W1, A1, B1, W2, A2, B2, out_pf);
  fin_kernel<<<256, 256, 0, stream>>>(Wd2, bd2);
  inter_kernel<<<64, 256, 0, stream>>>();
  sample_kernel<<<1, 256, 0, stream>>>(pos_coords, Wp, bp, bd1);
  dec_kernel<<<512, 256, 0, stream>>>(Wd2, bd2, out0);
}

// Round 13
// 149.645 us; speedup vs baseline: 1.5106x; 1.2400x over previous
//
#include <hip/hip_runtime.h>

// ---------------- problem constants ----------------
#define B_  2
#define N_  8192
#define I_  32
#define E_  128
#define H_  64
#define BN_ (B_*N_)          // 16384
#define NW_ (N_/64)          // 128 u64 words per (b,i) mask row

typedef unsigned long long u64;

// ---------------- module-scope device state (fully rewritten every launch) -----
__device__ float g_pe  [B_*I_*E_];     // pos_embed
__device__ float g_v1  [B_*I_*H_];     // decode hidden bias, initial
__device__ float g_v2  [B_*I_*H_];     // decode hidden bias, refined
__device__ float g_wd1t[E_*H_];        // Wd1 transposed [e][k]
__device__ float g_delta[B_*I_*E_];    // pos_embed - neg_embed
__device__ float g_u   [H_*BN_];       // u[k][p] (4 MB, k-major -> coalesced)
__device__ u64   g_masks[B_*I_*NW_];   // initial masks as bitwords (64 KB)
__device__ int   g_inter[B_*I_*I_];    // intersection counts (diag = m_sum)

// ---------------- jax threefry2x32, key = key(42) = (0,42) ----------------
__device__ __forceinline__ unsigned rotl_(unsigned x, unsigned n){ return (x<<n)|(x>>(32u-n)); }

__device__ void threefry_42(unsigned x0, unsigned x1, unsigned* r0, unsigned* r1){
  const unsigned ks0 = 0u, ks1 = 42u, ks2 = 0x1BD11BDAu ^ 0u ^ 42u;
  x0 += ks0; x1 += ks1;
  x0+=x1; x1=rotl_(x1,13); x1^=x0;
  x0+=x1; x1=rotl_(x1,15); x1^=x0;
  x0+=x1; x1=rotl_(x1,26); x1^=x0;
  x0+=x1; x1=rotl_(x1, 6); x1^=x0;
  x0+=ks1; x1+=ks2+1u;
  x0+=x1; x1=rotl_(x1,17); x1^=x0;
  x0+=x1; x1=rotl_(x1,29); x1^=x0;
  x0+=x1; x1=rotl_(x1,16); x1^=x0;
  x0+=x1; x1=rotl_(x1,24); x1^=x0;
  x0+=ks2; x1+=ks0+2u;
  x0+=x1; x1=rotl_(x1,13); x1^=x0;
  x0+=x1; x1=rotl_(x1,15); x1^=x0;
  x0+=x1; x1=rotl_(x1,26); x1^=x0;
  x0+=x1; x1=rotl_(x1, 6); x1^=x0;
  x0+=ks0; x1+=ks1+3u;
  x0+=x1; x1=rotl_(x1,17); x1^=x0;
  x0+=x1; x1=rotl_(x1,29); x1^=x0;
  x0+=x1; x1=rotl_(x1,16); x1^=x0;
  x0+=x1; x1=rotl_(x1,24); x1^=x0;
  x0+=ks1; x1+=ks2+4u;
  x0+=x1; x1=rotl_(x1,13); x1^=x0;
  x0+=x1; x1=rotl_(x1,15); x1^=x0;
  x0+=x1; x1=rotl_(x1,26); x1^=x0;
  x0+=x1; x1=rotl_(x1, 6); x1^=x0;
  x0+=ks2; x1+=ks0+5u;
  *r0 = x0; *r1 = x1;
}

// element e of jax.random.uniform(key(42), (2,32,32), 1e-20, 1.0)
// PARTITIONABLE threefry (VERIFIED r7): counter (0,e), bits = out0 ^ out1.
__device__ float jax_uniform_2048(int e){
  unsigned o0, o1;
  threefry_42(0u, (unsigned)e, &o0, &o1);
  unsigned bits = o0 ^ o1;
  float u = __uint_as_float((bits >> 9) | 0x3f800000u) - 1.0f;
  u = u + 1e-20f;
  return fmaxf(1e-20f, u);
}

// ---------------- K0: pos_embed + Wd1^T + v1 (64 blocks, 1 row each) ----------
__global__ void __launch_bounds__(256) prep_kernel(
    const float* __restrict__ pos_coords,
    const float* __restrict__ Wp, const float* __restrict__ bp,
    const float* __restrict__ Wd1,const float* __restrict__ bd1)
{
  __shared__ float t_l [E_*65];      // Wd1^T tile [e][k], pad 65: 33.3 KB
  __shared__ float pe_l[E_];
  const int row = blockIdx.x;        // 0..63 = b*I+i
  const int tid = threadIdx.x;

  // full Wd1 -> LDS transpose (coalesced reads; stride-65 banks)
  for (int idx = tid; idx < H_*E_; idx += 256){
    int k = idx >> 7, e = idx & 127;
    t_l[e*65 + k] = Wd1[idx];
  }
  if (tid < E_){
    const int e = tid;
    float s = pos_coords[row*3+0] * Wp[e*3+0];
    s = fmaf(pos_coords[row*3+1], Wp[e*3+1], s);
    s = fmaf(pos_coords[row*3+2], Wp[e*3+2], s);
    const float pe = s + bp[e];
    g_pe[row*E_ + e] = pe;
    pe_l[e] = pe;
  }
  __syncthreads();

  // block 0 publishes g_wd1t (coalesced)
  if (row == 0){
    for (int idx = tid; idx < E_*H_; idx += 256){
      int e = idx >> 6, k = idx & 63;
      g_wd1t[idx] = t_l[e*65 + k];
    }
  }
  // v1[row][k]: full 128-e chain (bit-identical to previous rounds)
  if (tid < H_){
    const int k = tid;
    float s = 0.f;
    for (int e = 0; e < 128; ++e)
      s = fmaf(pe_l[e], t_l[e*65 + k], s);
    g_v1[row*H_ + k] = s + bd1[k];
  }
}

// ---------------- K1: FUSED encoder + full u reduction + initial ballot -------
// 256 blocks x 512 threads; block = 64 points; wave w covers e in [w*16, w*16+16)
__global__ void __launch_bounds__(512) enc_kernel(
    const float* __restrict__ points,
    const float* __restrict__ W1, const float* __restrict__ A1,
    const float* __restrict__ B1, const float* __restrict__ W2,
    const float* __restrict__ A2, const float* __restrict__ B2,
    const float* __restrict__ Wd2,const float* __restrict__ bd2,
    float* __restrict__ out_pf)
{
  __shared__ float pf_l[E_*65];      // [e][point]: 33.3 KB
  __shared__ float u_l [64*65];      // [point][k]: 16.6 KB
  const int tid  = threadIdx.x;
  const int w_u  = __builtin_amdgcn_readfirstlane(tid >> 6);  // 0..7
  const int lane = tid & 63;
  const int p0   = blockIdx.x * 64;
  const int p    = p0 + lane;
  const int b    = blockIdx.x >> 7;

  const float x0 = points[p*3+0];
  const float x1 = points[p*3+1];
  const float x2 = points[p*3+2];

  float a1[4];
  #pragma unroll
  for (int r = 0; r < 4; ++r){
    float s = x0 * A1[r*3+0];
    s = fmaf(x1, A1[r*3+1], s);
    s = fmaf(x2, A1[r*3+2], s);
    a1[r] = s;
  }
  float t1[64];
  #pragma unroll
  for (int k = 0; k < 64; ++k){
    float s = x0 * W1[k*3+0];
    s = fmaf(x1, W1[k*3+1], s);
    s = fmaf(x2, W1[k*3+2], s);
    float l = a1[0] * B1[k*4+0];
    l = fmaf(a1[1], B1[k*4+1], l);
    l = fmaf(a1[2], B1[k*4+2], l);
    l = fmaf(a1[3], B1[k*4+3], l);
    t1[k] = fmaxf(fmaf(0.25f, l, s), 0.0f);
  }
  float a2[4];
  #pragma unroll
  for (int r = 0; r < 4; ++r){
    float s = 0.f;
    #pragma unroll
    for (int j = 0; j < 64; ++j) s = fmaf(t1[j], A2[r*64+j], s);
    a2[r] = s;
  }
  float u_p[64];
  #pragma unroll
  for (int k = 0; k < 64; ++k) u_p[k] = 0.f;

  const int e0 = w_u * 16;
  for (int ei = 0; ei < 16; ++ei){
    const int e = e0 + ei;                     // wave-uniform -> scalar loads
    float s1 = 0.f;
    #pragma unroll
    for (int j = 0; j < 64; ++j) s1 = fmaf(t1[j], W2[e*64+j], s1);
    float s2 = a2[0] * B2[e*4+0];
    s2 = fmaf(a2[1], B2[e*4+1], s2);
    s2 = fmaf(a2[2], B2[e*4+2], s2);
    s2 = fmaf(a2[3], B2[e*4+3], s2);
    const float pf = fmaf(0.25f, s2, s1);
    pf_l[e*65 + lane] = pf;                    // conflict-free
    #pragma unroll
    for (int k = 0; k < 64; ++k) u_p[k] = fmaf(pf, g_wd1t[e*64+k], u_p[k]);
  }

  // staged reduction of 8 wave partials, pass-order = e-order (bit-identical)
  for (int pass = 0; pass < 8; ++pass){
    if (w_u == pass){
      if (pass == 0){
        #pragma unroll
        for (int k = 0; k < 64; ++k) u_l[lane*65 + k] = u_p[k];
      } else {
        #pragma unroll
        for (int k = 0; k < 64; ++k) u_l[lane*65 + k] += u_p[k];
      }
    }
    __syncthreads();
  }

  // coalesced pf store (both halves)
  for (int idx = tid; idx < 64*E_; idx += 512){
    const int pt = idx >> 7, e = idx & 127;
    out_pf[(size_t)p0 * E_ + idx] = pf_l[e*65 + pt];
  }
  // coalesced u store: k-major
  for (int idx = tid; idx < 64*64; idx += 512){
    const int k = idx >> 6, pl = idx & 63;
    g_u[(size_t)k * BN_ + p0 + pl] = u_l[pl*65 + k];
  }

  // fused initial decode + ballot: wave w handles i in [w*4, w*4+4)
  const float bd2v = bd2[0];
  float acc[4];
  #pragma unroll
  for (int ii = 0; ii < 4; ++ii) acc[ii] = 0.f;
  const int ibase = w_u * 4;
  const float* v = g_v1 + ((b * I_ + ibase) << 6);
  for (int k = 0; k < 64; ++k){
    const float wd2k = Wd2[k];
    const float uk = u_l[lane*65 + k];
    #pragma unroll
    for (int ii = 0; ii < 4; ++ii)
      acc[ii] = fmaf(wd2k, fmaxf(uk + v[ii*64 + k], 0.0f), acc[ii]);
  }
  #pragma unroll
  for (int ii = 0; ii < 4; ++ii){
    const int i = ibase + ii;
    u64 bal = __ballot(acc[ii] + bd2v > 0.0f);
    if (lane == 0) g_masks[(size_t)(b * I_ + i) * NW_ + (blockIdx.x & 127)] = bal;
  }
}

// ---------------- K2a: inter[r][j] = popcount(m_r & m_j), 64 blocks ----------------
__global__ void __launch_bounds__(256) inter_kernel()
{
  const int r   = blockIdx.x;          // 0..63
  const int b   = r >> 5;
  const int tid = threadIdx.x;
  const int j   = tid >> 3;            // 0..31
  const int ws  = (tid & 7) * 16;      // word segment base
  const u64* mi = g_masks + (size_t)r * NW_;
  const u64* mj = g_masks + (size_t)(b*32 + j) * NW_;
  int s = 0;
  #pragma unroll
  for (int w = 0; w < 16; ++w)
    s += __popcll(mi[ws + w] & mj[ws + w]);
  s += __shfl_xor(s, 1, 64);
  s += __shfl_xor(s, 2, 64);
  s += __shfl_xor(s, 4, 64);
  if ((tid & 7) == 0) g_inter[r*32 + j] = s;
}

// ---------------- K2b: Gumbel-max sampling + delta (1 block) ----------------
__global__ void __launch_bounds__(256) sample_kernel(
    const float* __restrict__ pos_coords,
    const float* __restrict__ Wp, const float* __restrict__ bp)
{
  __shared__ int   inter_l[2048];
  __shared__ float nc_l[64][3];
  const int tid = threadIdx.x;

  for (int idx = tid; idx < 2048; idx += 256) inter_l[idx] = g_inter[idx];
  __syncthreads();

  if (tid < 64){
    const int b = tid >> 5;
    const int i = tid & 31;
    const int msum_i = inter_l[(b << 10) + (i << 5) + i];   // diag = m_sum
    float best = -INFINITY; int bestj = 0; bool any = false;
    for (int j = 0; j < 32; ++j){
      const int inter = inter_l[(b << 10) + (i << 5) + j];
      const int msum_j = inter_l[(b << 10) + (j << 5) + j];
      const int uni   = msum_i + msum_j - inter;
      // EXACT f32 mimicry of the reference: inter/(union+1e-6) in f32.
      const float iou = (float)inter / ((float)uni + 1e-6f);
      const bool cand = (j != i) && (iou >= 0.1f);
      if (cand){
        any = true;
        const float uu = jax_uniform_2048((tid << 5) + j);
        const float g  = -logf(-logf(uu));
        if (g > best){ best = g; bestj = j; }            // first-max like argmax
      }
    }
    nc_l[tid][0] = any ? pos_coords[(b*32 + bestj)*3 + 0] : 0.f;
    nc_l[tid][1] = any ? pos_coords[(b*32 + bestj)*3 + 1] : 0.f;
    nc_l[tid][2] = any ? pos_coords[(b*32 + bestj)*3 + 2] : 0.f;
  }
  __syncthreads();

  for (int idx = tid; idx < 64*E_; idx += 256){
    const int row = idx >> 7, e = idx & 127;
    float ne = nc_l[row][0] * Wp[e*3+0];
    ne = fmaf(nc_l[row][1], Wp[e*3+1], ne);
    ne = fmaf(nc_l[row][2], Wp[e*3+2], ne);
    ne = ne + bp[e];                                     // == bp when invalid
    g_delta[idx] = g_pe[idx] - ne;
  }
}

// ---------------- K2c: v2[row][k] (16 blocks) ----------------
__global__ void __launch_bounds__(256) v2k_kernel(const float* __restrict__ bd1)
{
  const int idx = blockIdx.x * 256 + threadIdx.x;   // 0..4095
  const int row = idx >> 6, k = idx & 63;
  float s = 0.f;
  for (int e = 0; e < 128; ++e)
    s = fmaf(g_delta[row*128 + e], g_wd1t[e*64 + k], s);  // uniform + coalesced
  g_v2[idx] = s + bd1[k];
}

// ---------------- K3: refined decode (512 blocks, i-halves) ------
__global__ void __launch_bounds__(256) dec_kernel(
    const float* __restrict__ Wd2, const float* __restrict__ bd2,
    float* __restrict__ out0)
{
  const int tid  = threadIdx.x;
  const int w_u  = __builtin_amdgcn_readfirstlane(tid >> 6);
  const int lane = tid & 63;
  const int bc   = blockIdx.x;           // 512 blocks
  const int b    = bc >> 8;
  const int nb   = (bc & 127) << 6;
  const int ih   = (bc >> 7) & 1;        // i-half
  const int n    = nb + lane;
  const int p    = b * N_ + n;

  float u[64];
  #pragma unroll
  for (int k = 0; k < 64; ++k) u[k] = g_u[(size_t)k * BN_ + p];   // coalesced

  const float bd2v = bd2[0];
  float acc[4];
  #pragma unroll
  for (int ii = 0; ii < 4; ++ii) acc[ii] = 0.f;
  const int ibase = ih * 16 + w_u * 4;
  const float* v = g_v2 + ((b * I_ + ibase) << 6);
  for (int k = 0; k < 64; ++k){
    const float wd2k = Wd2[k];
    const float uk = u[k];
    #pragma unroll
    for (int ii = 0; ii < 4; ++ii)
      acc[ii] = fmaf(wd2k, fmaxf(uk + v[ii*64 + k], 0.0f), acc[ii]);
  }
  #pragma unroll
  for (int ii = 0; ii < 4; ++ii){
    const int i = ibase + ii;
    out0[(size_t)(b * I_ + i) * N_ + n] = acc[ii] + bd2v;
  }
}

// ---------------- launch ----------------
extern "C" void kernel_launch(void* const* d_in, const int* in_sizes, int n_in,
                              void* d_out, int out_size, void* d_ws, size_t ws_size,
                              hipStream_t stream)
{
  (void)in_sizes; (void)n_in; (void)out_size; (void)d_ws; (void)ws_size;
  const float* points     = (const float*)d_in[0];
  const float* pos_coords = (const float*)d_in[1];
  const float* W1  = (const float*)d_in[2];
  const float* A1  = (const float*)d_in[3];
  const float* B1  = (const float*)d_in[4];
  const float* W2  = (const float*)d_in[5];
  const float* A2  = (const float*)d_in[6];
  const float* B2  = (const float*)d_in[7];
  const float* Wp  = (const float*)d_in[8];
  const float* bp  = (const float*)d_in[9];
  const float* Wd1 = (const float*)d_in[10];
  const float* bd1 = (const float*)d_in[11];
  const float* Wd2 = (const float*)d_in[12];
  const float* bd2 = (const float*)d_in[13];

  float* out0   = (float*)d_out;                        // refined_logits [B,I,N]
  float* out_pf = out0 + (size_t)B_ * I_ * N_;          // point_feats   [B,N,E]

  prep_kernel<<<64, 256, 0, stream>>>(pos_coords, Wp, bp, Wd1, bd1);
  enc_kernel<<<256, 512, 0, stream>>>(points, W1, A1, B1, W2, A2, B2,
                                      Wd2, bd2, out_pf);
  inter_kernel<<<64, 256, 0, stream>>>();
  sample_kernel<<<1, 256, 0, stream>>>(pos_coords, Wp, bp);
  v2k_kernel<<<16, 256, 0, stream>>>(bd1);
  dec_kernel<<<512, 256, 0, stream>>>(Wd2, bd2, out0);
}